// Round 15
// baseline (305.353 us; speedup 1.0000x reference)
//
#include <hip/hip_runtime.h>
#include <hip/hip_bf16.h>

#define NN 3072
#define NWORD 96
#define HH 8

typedef short short8 __attribute__((ext_vector_type(8)));
typedef float float4v __attribute__((ext_vector_type(4)));
typedef unsigned short ushort4v __attribute__((ext_vector_type(4)));

__device__ __forceinline__ float bf2f(unsigned short u) {
  union { unsigned u; float f; } v; v.u = ((unsigned)u) << 16; return v.f;
}
__device__ __forceinline__ unsigned short f2bf(float f) {
  union { float f; unsigned u; } v; v.f = f;
  unsigned r = v.u + 0x7fffu + ((v.u >> 16) & 1u);
  return (unsigned short)(r >> 16);
}
// flag==1 -> buffers are bf16; flag==0 -> fp32
__device__ __forceinline__ float ldin(const void* p, size_t i, int isbf) {
  return isbf ? bf2f(((const unsigned short*)p)[i]) : ((const float*)p)[i];
}

// ---- dtype detect ----
__global__ __launch_bounds__(256) void k_detect(const unsigned* __restrict__ aw,
                                                int* __restrict__ flag) {
  __shared__ int s;
  if (threadIdx.x == 0) s = 0;
  __syncthreads();
  int any = 0;
  for (int i = threadIdx.x; i < 16384; i += 256)
    any |= ((aw[i] & 0xFFFFu) != 0u);
  if (any) s = 1;   // benign race
  __syncthreads();
  if (threadIdx.x == 0) *flag = s;
}

// ---- build TRANSPOSED bitmask, grid-strided (1536 blocks, 24 chunks each) ----
__global__ __launch_bounds__(256) void k_mask(const void* __restrict__ adj,
                                              const int* __restrict__ flag,
                                              unsigned* __restrict__ maskT) {
  int isbf = *flag;
  int t = threadIdx.x;
  int lane = t & 63;
  for (int chunk = blockIdx.x; chunk < NN * 12; chunk += gridDim.x) {
    int row = chunk / 12;
    int seg = chunk - row * 12;
    int j = seg * 256 + t;
    bool pred = ldin(adj, (size_t)row * NN + j, isbf) != 0.f;
    unsigned long long b = __ballot(pred);
    int word = seg * 8 + (t >> 6) * 2;
    if (lane == 0) maskT[(size_t)word * NN + row] = (unsigned)b;
    else if (lane == 32) maskT[(size_t)(word + 1) * NN + row] = (unsigned)(b >> 32);
  }
}

// ---- prep: mergeState (4 row-chunks per block) + all three weight transposes ----
__global__ __launch_bounds__(256) void k_prep(const void* __restrict__ x,
                                              const int* __restrict__ obs,
                                              const void* __restrict__ theta,
                                              const void* __restrict__ W0,
                                              const void* __restrict__ W1,
                                              const void* __restrict__ Wo,
                                              const int* __restrict__ flag,
                                              unsigned short* __restrict__ h_bf,
                                              unsigned short* __restrict__ W0T,
                                              unsigned short* __restrict__ W1T,
                                              unsigned short* __restrict__ WoT) {
  __shared__ __align__(16) unsigned short tile[16][17];
  int isbf = *flag;
  int t = threadIdx.x;
  int b = blockIdx.x;
  if (b < NN / 4) {                      // mergeState: 1024 elems per block
    for (int i = b * 1024 + t; i < b * 1024 + 1024; i += 256) {
      int row = i >> 8, c = i & 255;
      float v = ldin(x, i, isbf);
      if (obs[row] == 1) v += ldin(theta, c, isbf);
      h_bf[i] = f2bf(v);
    }
    return;
  }
  b -= NN / 4;
  const void* in; unsigned short* out; int R, C, r0, c0;
  if (b < 1024) {                        // W0: 8 heads x (16 x 8) tiles, 256x128
    int h = b >> 7, rem = b & 127;
    in = (const char*)W0 + (size_t)h * 256 * 128 * (isbf ? 2 : 4);
    out = W0T + (size_t)h * 256 * 128;
    R = 256; C = 128; r0 = (rem >> 3) * 16; c0 = (rem & 7) * 16;
  } else if (b < 1536) {                 // W1: 8 heads x (8 x 8), 128x128
    b -= 1024;
    int h = b >> 6, rem = b & 63;
    in = (const char*)W1 + (size_t)h * 128 * 128 * (isbf ? 2 : 4);
    out = W1T + (size_t)h * 128 * 128;
    R = 128; C = 128; r0 = (rem >> 3) * 16; c0 = (rem & 7) * 16;
  } else {                               // Wo: (64 x 4), 1024x64
    b -= 1536;
    in = Wo; out = WoT;
    R = 1024; C = 64; r0 = (b >> 2) * 16; c0 = (b & 3) * 16;
  }
  int tc = t & 15, tr = t >> 4;
  tile[tr][tc] = f2bf(ldin(in, (size_t)(r0 + tr) * C + (c0 + tc), isbf));
  __syncthreads();
  out[(size_t)(c0 + tr) * R + (r0 + tc)] = tile[tc][tr];
}

// ---- fused GEMM: 32 rows x 128 cols/block; head = blk % HH pins writes ----
template<int K>
__global__ __launch_bounds__(256) void k_gemm_fused(const unsigned short* __restrict__ A,
                                                    const unsigned short* __restrict__ WT,
                                                    unsigned short* __restrict__ WhTf,
                                                    long aOff, long wOff,
                                                    const void* __restrict__ avec,
                                                    const int* __restrict__ flag,
                                                    float* __restrict__ f1,
                                                    float* __restrict__ f2) {
  __shared__ __align__(16) unsigned short tile[4][2][32][17];
  __shared__ float avs[256];
  __shared__ float fp[2][8][32];
  int isbf = *flag;
  int head = blockIdx.x % HH;            // XCD pin
  int jb = blockIdx.x / HH;
  A += (size_t)head * aOff; WT += (size_t)head * wOff;
  int rowbase = jb * 32;
  int t = threadIdx.x;
  int w = t >> 6, lane = t & 63;
  int q = lane >> 4, l = lane & 15;
  int colbase = w * 32;
  avs[t] = ldin(avec, (size_t)head * 256 + t, isbf);
  float4v acc[2][2];
#pragma unroll
  for (int rt = 0; rt < 2; rt++)
#pragma unroll
    for (int ct = 0; ct < 2; ct++) { float4v z = {0.f, 0.f, 0.f, 0.f}; acc[rt][ct] = z; }

  for (int kb = 0; kb < K; kb += 32) {
    short8 af[2], bfr[2];
#pragma unroll
    for (int rt = 0; rt < 2; rt++)
      af[rt] = *(const short8*)(A + (size_t)(rowbase + rt * 16 + l) * K + kb + q * 8);
#pragma unroll
    for (int ct = 0; ct < 2; ct++)
      bfr[ct] = *(const short8*)(WT + (size_t)(colbase + ct * 16 + l) * K + kb + q * 8);
#pragma unroll
    for (int rt = 0; rt < 2; rt++)
#pragma unroll
      for (int ct = 0; ct < 2; ct++)
        acc[rt][ct] = __builtin_amdgcn_mfma_f32_16x16x32_bf16(af[rt], bfr[ct], acc[rt][ct], 0, 0, 0);
  }
#pragma unroll
  for (int rt = 0; rt < 2; rt++)
#pragma unroll
    for (int ct = 0; ct < 2; ct++)
#pragma unroll
      for (int reg = 0; reg < 4; reg++)
        tile[w][ct][rt * 16 + q * 4 + reg][l] = f2bf(acc[rt][ct][reg]);
  __syncthreads();
#pragma unroll
  for (int ct = 0; ct < 2; ct++) {
    short8 r8;
#pragma unroll
    for (int i = 0; i < 8; i++) r8[i] = tile[w][ct][q * 8 + i][l];
    size_t chunk = ((size_t)head * (NN / 32) + jb) * 8 + (w * 2 + ct);
    *(short8*)(WhTf + chunk * 512 + lane * 8) = r8;
  }
  {
    int r = t & 31, g = t >> 5;
    int ww = g >> 1, cc = g & 1;
    float s1 = 0.f, s2 = 0.f;
#pragma unroll
    for (int li = 0; li < 16; li++) {
      float v = bf2f(tile[ww][cc][r][li]);
      s1 += v * avs[g * 16 + li];
      s2 += v * avs[128 + g * 16 + li];
    }
    fp[0][g][r] = s1; fp[1][g][r] = s2;
  }
  __syncthreads();
  if (t < 32) {
    float s1 = 0.f, s2 = 0.f;
#pragma unroll
    for (int g2 = 0; g2 < 8; g2++) { s1 += fp[0][g2][t]; s2 += fp[1][g2][t]; }
    f1[head * NN + rowbase + t] = s1;
    f2[head * NN + rowbase + t] = s2;
  }
}

// ---- out-layer GEMM, K split across blocks into fp32 partials ----
template<int K, int KS>
__global__ __launch_bounds__(256) void k_gemm_out(const unsigned short* __restrict__ A,
                                                  const unsigned short* __restrict__ WT,
                                                  float* __restrict__ gpart) {
  constexpr int KC = K / KS;
  int ks = blockIdx.y;
  int rowbase = blockIdx.x * 16;
  int t = threadIdx.x;
  int w = t >> 6, lane = t & 63;
  int q = lane >> 4, l = lane & 15;
  int colbase = w * 16;
  float4v acc = {0.f, 0.f, 0.f, 0.f};
  for (int kb = ks * KC; kb < ks * KC + KC; kb += 32) {
    short8 af = *(const short8*)(A + (size_t)(rowbase + l) * K + kb + q * 8);
    short8 bfr = *(const short8*)(WT + (size_t)(colbase + l) * K + kb + q * 8);
    acc = __builtin_amdgcn_mfma_f32_16x16x32_bf16(af, bfr, acc, 0, 0, 0);
  }
#pragma unroll
  for (int reg = 0; reg < 4; reg++) {
    int r = rowbase + q * 4 + reg;
    int n = colbase + l;
    gpart[((size_t)ks * 64 + n) * NN + r] = acc[reg];
  }
}

// ---- combine K-split partials, emit WhoTf in fragment order (DC=64) ----
template<int KS>
__global__ __launch_bounds__(256) void k_gemm_red(const float* __restrict__ gpart,
                                                  unsigned short* __restrict__ WhoTf) {
  int tid = blockIdx.x * 256 + threadIdx.x;
  int r = tid % NN, n = tid / NN;
  float s = 0.f;
#pragma unroll
  for (int ks = 0; ks < KS; ks++) s += gpart[((size_t)ks * 64 + n) * NN + r];
  int jb = r >> 5, q = (r >> 3) & 3, i = r & 7, ct = n >> 4, l = n & 15;
  WhoTf[((size_t)(jb * 4 + ct)) * 512 + (q * 16 + l) * 8 + i] = f2bf(s);
}

// ---- f1/f2 from fragment-order WhTf (out layer only) ----
template<int DC>
__global__ __launch_bounds__(256) void k_f12f(const unsigned short* __restrict__ WhTf,
                                              const void* __restrict__ avec,
                                              const int* __restrict__ flag,
                                              float* __restrict__ f1, float* __restrict__ f2) {
  constexpr int NCT = DC / 16;
  int isbf = *flag;
  int head = blockIdx.y;
  int w = threadIdx.x >> 6, lane = threadIdx.x & 63;
  int q = lane >> 4, l = lane & 15;
  int jbIdx = blockIdx.x * 4 + w;
  size_t abase = (size_t)head * 2 * DC;
  float s1[8], s2[8];
#pragma unroll
  for (int i = 0; i < 8; i++) { s1[i] = 0.f; s2[i] = 0.f; }
#pragma unroll
  for (int ct = 0; ct < NCT; ct++) {
    short8 v = *(const short8*)(WhTf + (((size_t)head * (NN / 32) + jbIdx) * NCT + ct) * 512 + lane * 8);
    float a1v = ldin(avec, abase + ct * 16 + l, isbf);
    float a2v = ldin(avec, abase + DC + ct * 16 + l, isbf);
#pragma unroll
    for (int i = 0; i < 8; i++) {
      float f = bf2f((unsigned short)v[i]);
      s1[i] += f * a1v;
      s2[i] += f * a2v;
    }
  }
#pragma unroll
  for (int d = 1; d < 16; d <<= 1)
#pragma unroll
    for (int i = 0; i < 8; i++) {
      s1[i] += __shfl_xor(s1[i], d, 64);
      s2[i] += __shfl_xor(s2[i], d, 64);
    }
  if (l == 0) {
    int r = jbIdx * 32 + q * 8;
#pragma unroll
    for (int i = 0; i < 8; i++) {
      f1[head * NN + r + i] = s1[i];
      f2[head * NN + r + i] = s2[i];
    }
  }
}

// ---- attention partial: 16-row waves, 64-row blocks, S j-chunks (S=4 big):
//      halves pnum footprint vs r14 (25 MB, ~3.1 MB/head -> L2-friendly).
//      LDS-staged B (double-buffered, post-barrier prefetch), f2+mask staged,
//      ones-MFMA denominator, bf16 frag-order partials, head XCD-pinned ----
template<int DCOL, int S>
__global__ __launch_bounds__(256, 4) void k_attn_part(
    const unsigned* __restrict__ maskT,
    const float* __restrict__ f1g, const float* __restrict__ f2g,
    const unsigned short* __restrict__ WhTf,
    unsigned short* __restrict__ pnum, float* __restrict__ pden, int NH) {
  constexpr int NCT = DCOL / 16;
  constexpr int JCH = NN / S;
  constexpr int NIT = JCH / 32;
  constexpr int CH = NCT * 512;
  constexpr int GR = CH / (256 * 8);
  __shared__ __align__(16) unsigned short Bs[2][CH];
  __shared__ __align__(16) float f2s[JCH];
  __shared__ unsigned ms[NIT * 64];

  int blk = blockIdx.x;
  int head = blk % NH;
  int rest = blk / NH;
  int js = rest % S;
  int bx = rest / S;
  int t = threadIdx.x;
  int w = t >> 6, lane = t & 63;
  int q = lane >> 4, l = lane & 15;
  int rowblk = bx * 64;
  int rowbase = rowblk + w * 16;
  size_t headJB = (size_t)head * (NN / 32);
  int j0 = js * JCH;

  for (int i = t; i < JCH; i += 256) f2s[i] = f2g[head * NN + j0 + i];
  for (int i = t; i < NIT * 64; i += 256)
    ms[i] = maskT[(size_t)((j0 >> 5) + (i >> 6)) * NN + rowblk + (i & 63)];
  float f1c = f1g[head * NN + rowbase + l] * 1.44269504f;

  short8 ones;
#pragma unroll
  for (int i = 0; i < 8; i++) ones[i] = (short)0x3F80;

  float4v acc[NCT];
#pragma unroll
  for (int ct = 0; ct < NCT; ct++) { float4v z = {0.f, 0.f, 0.f, 0.f}; acc[ct] = z; }
  float4v accd = {0.f, 0.f, 0.f, 0.f};

  short8 stg[GR];
  {
    const unsigned short* g0 = WhTf + (headJB + (j0 >> 5)) * (size_t)CH;
#pragma unroll
    for (int g = 0; g < GR; g++) stg[g] = *(const short8*)(g0 + g * 2048 + t * 8);
  }

  int cur = 0;
  for (int it = 0; it < NIT; it++) {
#pragma unroll
    for (int g = 0; g < GR; g++)
      *(short8*)(&Bs[cur][g * 2048 + t * 8]) = stg[g];
    __syncthreads();                       // covers f2s/ms staging on it==0 too
    int itn = (it + 1 < NIT) ? it + 1 : 0;
    const unsigned short* gn = WhTf + (headJB + (j0 >> 5) + itn) * (size_t)CH;
#pragma unroll
    for (int g = 0; g < GR; g++) stg[g] = *(const short8*)(gn + g * 2048 + t * 8);

    unsigned mwc = ms[it * 64 + (w * 16 + l)] >> (q * 8);
    float4v fac = *(const float4v*)(&f2s[it * 32 + q * 8]);
    float4v fbc = *(const float4v*)(&f2s[it * 32 + q * 8 + 4]);
    short8 bfr[NCT];
#pragma unroll
    for (int ct = 0; ct < NCT; ct++)
      bfr[ct] = *(const short8*)(&Bs[cur][ct * 512 + lane * 8]);

    float p[8];
#pragma unroll
    for (int i = 0; i < 8; i++) {
      float fv = (i < 4) ? fac[i] : fbc[i - 4];
      float t0 = fmaf(fv, 1.44269504f, f1c);
      t0 = __builtin_amdgcn_fmed3f(t0, 0.2f * t0, 43.f);
      t0 = (mwc & (1u << i)) ? t0 : -200.f;
      p[i] = exp2f(t0);
    }
    union { __hip_bfloat162 b2[4]; short8 s8; } u0;
#pragma unroll
    for (int k = 0; k < 4; k++)
      u0.b2[k] = __float22bfloat162_rn({p[2 * k], p[2 * k + 1]});
    accd = __builtin_amdgcn_mfma_f32_16x16x32_bf16(u0.s8, ones, accd, 0, 0, 0);
#pragma unroll
    for (int ct = 0; ct < NCT; ct++)
      acc[ct] = __builtin_amdgcn_mfma_f32_16x16x32_bf16(u0.s8, bfr[ct], acc[ct], 0, 0, 0);
    cur ^= 1;
  }

  size_t slab = (size_t)(js * NH + head);
  if (l == 0) {   // accd replicated across cols; lanes 0,16,32,48 cover 16 rows
#pragma unroll
    for (int reg = 0; reg < 4; reg++)
      pden[slab * NN + rowbase + q * 4 + reg] = accd[reg];
  }
  int trb = rowbase >> 4;
#pragma unroll
  for (int ct = 0; ct < NCT; ct++) {
    ushort4v u;
    u.x = f2bf(acc[ct].x); u.y = f2bf(acc[ct].y);
    u.z = f2bf(acc[ct].z); u.w = f2bf(acc[ct].w);
    size_t cidx = ((slab * (NN / 16) + trb) * NCT + ct) * 256 + lane * 4;
    *(ushort4v*)(pnum + cidx) = u;
  }
}

// ---- combine partials: 4 elems/thread, head-pinned ----
template<int DCOL, int S>
__global__ __launch_bounds__(256) void k_attn_reduce(
    const unsigned short* __restrict__ pnum, const float* __restrict__ pden,
    void* __restrict__ outg, long outHeadOff, int outRowStride, int NH,
    const int* __restrict__ flag, int finalOut) {
  constexpr int NCT = DCOL / 16;
  int blk = blockIdx.x;
  int h = blk % NH;
  int bi = blk / NH;
  int t = threadIdx.x;
  int base = bi * 1024 + t * 4;
  int tile = base >> 8;
  int lane = (base >> 2) & 63;
  int ct = tile % NCT, tr = tile / NCT;
  int q = lane >> 4, l = lane & 15;
  int row0 = tr * 16 + q * 4;
  int col = ct * 16 + l;
  float sn[4] = {0.f, 0.f, 0.f, 0.f};
  float sd[4] = {0.f, 0.f, 0.f, 0.f};
#pragma unroll
  for (int js = 0; js < S; js++) {
    size_t sl = (size_t)(js * NH + h);
    ushort4v pv = *(const ushort4v*)(pnum + sl * (size_t)(NN * DCOL) + base);
    float4v dv = *(const float4v*)(pden + sl * NN + row0);
    sn[0] += bf2f(pv.x); sn[1] += bf2f(pv.y); sn[2] += bf2f(pv.z); sn[3] += bf2f(pv.w);
    sd[0] += dv.x; sd[1] += dv.y; sd[2] += dv.z; sd[3] += dv.w;
  }
  int f32o = finalOut && (*flag == 0);
#pragma unroll
  for (int r = 0; r < 4; r++) {
    float v = sd[r] > 0.f ? sn[r] / sd[r] : 0.f;
    v = v > 0.f ? v : expm1f(v);           // ELU
    size_t idx = (size_t)h * outHeadOff + (size_t)(row0 + r) * outRowStride + col;
    if (f32o) ((float*)outg)[idx] = v;
    else ((unsigned short*)outg)[idx] = f2bf(v);
  }
}

extern "C" void kernel_launch(void* const* d_in, const int* in_sizes, int n_in,
                              void* d_out, int out_size, void* d_ws, size_t ws_size,
                              hipStream_t stream) {
  const void* x     = d_in[0];
  const void* adj   = d_in[1];
  const int*  obs   = (const int*)d_in[2];
  // d_in[3] s_mat unused (method='base')
  const void* theta = d_in[4];
  const void* W0    = d_in[5];
  const void* a0    = d_in[6];
  const void* W1    = d_in[7];
  const void* a1    = d_in[8];
  const void* Wo    = d_in[9];
  const void* ao    = d_in[10];

  char* ws = (char*)d_ws;
  size_t off = 0;
  auto alloc = [&](size_t bytes) { void* p = ws + off; off += (bytes + 255) & ~(size_t)255; return p; };
  int*            flag  = (int*)alloc(4);
  unsigned*       maskT = (unsigned*)alloc((size_t)NN * NWORD * 4);
  unsigned short* h_bf  = (unsigned short*)alloc((size_t)NN * 256 * 2);
  unsigned short* WhTf  = (unsigned short*)alloc((size_t)HH * 128 * NN * 2);
  float*          f1    = (float*)alloc((size_t)HH * NN * 4);
  float*          f2    = (float*)alloc((size_t)HH * NN * 4);
  unsigned short* h0    = (unsigned short*)alloc((size_t)HH * NN * 128 * 2);
  unsigned short* hc    = (unsigned short*)alloc((size_t)NN * 1024 * 2);
  unsigned short* W0T   = (unsigned short*)alloc((size_t)HH * 128 * 256 * 2);
  unsigned short* W1T   = (unsigned short*)alloc((size_t)HH * 128 * 128 * 2);
  unsigned short* WoT   = (unsigned short*)alloc((size_t)64 * 1024 * 2);
  unsigned short* WhoTf = (unsigned short*)alloc((size_t)64 * NN * 2);
  float*          fo1   = (float*)alloc((size_t)NN * 4);
  float*          fo2   = (float*)alloc((size_t)NN * 4);
  float*          gpart = (float*)alloc((size_t)4 * 64 * NN * 4);

  // partial buffers: S=4 big layers (25 MB bf16), final layer S=32 (12.6 MB)
  unsigned short* pnum = (unsigned short*)alloc((size_t)4 * HH * NN * 128 * 2);
  float* pden = (float*)alloc((size_t)32 * NN * 4);

  k_detect<<<1, 256, 0, stream>>>((const unsigned*)adj, flag);
  k_mask<<<1536, 256, 0, stream>>>(adj, flag, maskT);
  k_prep<<<NN / 4 + 1792, 256, 0, stream>>>(x, obs, theta, W0, W1, Wo, flag,
                                            h_bf, W0T, W1T, WoT);

  // ---- layer 0 ----
  k_gemm_fused<256><<<(NN / 32) * HH, 256, 0, stream>>>(h_bf, W0T, WhTf,
                                                        0, 128 * 256, a0, flag, f1, f2);
  k_attn_part<128, 4><<<(NN / 64) * 4 * HH, 256, 0, stream>>>(maskT, f1, f2, WhTf, pnum, pden, HH);
  k_attn_reduce<128, 4><<<HH * NN * 128 / 1024, 256, 0, stream>>>(pnum, pden, h0, (long)NN * 128, 128, HH, flag, 0);
  // ---- layer 1 ----
  k_gemm_fused<128><<<(NN / 32) * HH, 256, 0, stream>>>(h0, W1T, WhTf,
                                                        (long)NN * 128, 128 * 128, a1, flag, f1, f2);
  k_attn_part<128, 4><<<(NN / 64) * 4 * HH, 256, 0, stream>>>(maskT, f1, f2, WhTf, pnum, pden, HH);
  k_attn_reduce<128, 4><<<HH * NN * 128 / 1024, 256, 0, stream>>>(pnum, pden, hc, 128, 1024, HH, flag, 0);
  // ---- output layer ----
  k_gemm_out<1024, 4><<<dim3(NN / 16, 4), 256, 0, stream>>>(hc, WoT, gpart);
  k_gemm_red<4><<<64 * NN / 256, 256, 0, stream>>>(gpart, WhoTf);
  k_f12f<64><<<dim3(NN / 128, 1), 256, 0, stream>>>(WhoTf, ao, flag, fo1, fo2);
  k_attn_part<64, 32><<<(NN / 64) * 32, 256, 0, stream>>>(maskT, fo1, fo2, WhoTf, pnum, pden, 1);
  k_attn_reduce<64, 32><<<NN * 64 / 1024, 256, 0, stream>>>(pnum, pden, d_out, 0, 64, 1, flag, 1);
}

// Round 16
// 274.666 us; speedup vs baseline: 1.1117x; 1.1117x over previous
//
#include <hip/hip_runtime.h>
#include <hip/hip_bf16.h>

#define NN 3072
#define HH 8

typedef short short8 __attribute__((ext_vector_type(8)));
typedef float float4v __attribute__((ext_vector_type(4)));
typedef unsigned short ushort4v __attribute__((ext_vector_type(4)));

__device__ __forceinline__ float bf2f(unsigned short u) {
  union { unsigned u; float f; } v; v.u = ((unsigned)u) << 16; return v.f;
}
__device__ __forceinline__ unsigned short f2bf(float f) {
  union { float f; unsigned u; } v; v.f = f;
  unsigned r = v.u + 0x7fffu + ((v.u >> 16) & 1u);
  return (unsigned short)(r >> 16);
}
// flag==1 -> buffers are bf16; flag==0 -> fp32
__device__ __forceinline__ float ldin(const void* p, size_t i, int isbf) {
  return isbf ? bf2f(((const unsigned short*)p)[i]) : ((const float*)p)[i];
}
// per-wave dtype detect: scan adj's first 4KB. bf16 adj has ~5% low-half 0x3F80
// words (P(none in 2048 elems) ~ e^-52); fp32 {0,1} words always have low16==0.
__device__ __forceinline__ int detect_bf(const void* adj) {
  const unsigned* aw = (const unsigned*)adj;
  int lane = threadIdx.x & 63;
  unsigned o = 0;
#pragma unroll
  for (int i = 0; i < 16; i++) o |= aw[lane + i * 64] & 0xFFFFu;
  return __ballot(o != 0) != 0ull;
}

// ---- fused prep: transposed bitmask (blocks 0..1536, grid-strided) +
//      mergeState + 3 weight transposes (blocks 1536..4096) ----
__global__ __launch_bounds__(256) void k_maskprep(const void* __restrict__ adj,
                                                  unsigned* __restrict__ maskT,
                                                  const void* __restrict__ x,
                                                  const int* __restrict__ obs,
                                                  const void* __restrict__ theta,
                                                  const void* __restrict__ W0,
                                                  const void* __restrict__ W1,
                                                  const void* __restrict__ Wo,
                                                  unsigned short* __restrict__ h_bf,
                                                  unsigned short* __restrict__ W0T,
                                                  unsigned short* __restrict__ W1T,
                                                  unsigned short* __restrict__ WoT) {
  __shared__ __align__(16) unsigned short tile[16][17];
  int isbf = detect_bf(adj);
  int t = threadIdx.x;
  if (blockIdx.x < 1536) {               // bitmask, grid-strided
    int lane = t & 63;
    for (int chunk = blockIdx.x; chunk < NN * 12; chunk += 1536) {
      int row = chunk / 12;
      int seg = chunk - row * 12;
      int j = seg * 256 + t;
      bool pred = ldin(adj, (size_t)row * NN + j, isbf) != 0.f;
      unsigned long long b = __ballot(pred);
      int word = seg * 8 + (t >> 6) * 2;
      if (lane == 0) maskT[(size_t)word * NN + row] = (unsigned)b;
      else if (lane == 32) maskT[(size_t)(word + 1) * NN + row] = (unsigned)(b >> 32);
    }
    return;
  }
  int b = blockIdx.x - 1536;
  if (b < NN / 4) {                      // mergeState: 1024 elems per block
    for (int i = b * 1024 + t; i < b * 1024 + 1024; i += 256) {
      int row = i >> 8, c = i & 255;
      float v = ldin(x, i, isbf);
      if (obs[row] == 1) v += ldin(theta, c, isbf);
      h_bf[i] = f2bf(v);
    }
    return;
  }
  b -= NN / 4;
  const void* in; unsigned short* out; int R, C, r0, c0;
  if (b < 1024) {                        // W0: 8 heads x (16 x 8) tiles, 256x128
    int h = b >> 7, rem = b & 127;
    in = (const char*)W0 + (size_t)h * 256 * 128 * (isbf ? 2 : 4);
    out = W0T + (size_t)h * 256 * 128;
    R = 256; C = 128; r0 = (rem >> 3) * 16; c0 = (rem & 7) * 16;
  } else if (b < 1536) {                 // W1: 8 heads x (8 x 8), 128x128
    b -= 1024;
    int h = b >> 6, rem = b & 63;
    in = (const char*)W1 + (size_t)h * 128 * 128 * (isbf ? 2 : 4);
    out = W1T + (size_t)h * 128 * 128;
    R = 128; C = 128; r0 = (rem >> 3) * 16; c0 = (rem & 7) * 16;
  } else {                               // Wo: (64 x 4), 1024x64
    b -= 1536;
    in = Wo; out = WoT;
    R = 1024; C = 64; r0 = (b >> 2) * 16; c0 = (b & 3) * 16;
  }
  int tc = t & 15, tr = t >> 4;
  tile[tr][tc] = f2bf(ldin(in, (size_t)(r0 + tr) * C + (c0 + tc), isbf));
  __syncthreads();
  out[(size_t)(c0 + tr) * R + (r0 + tc)] = tile[tc][tr];
}

// ---- layer-0 fused GEMM: A from h_bf; writes WhTf (B-frag order) + f1/f2 ----
template<int K>
__global__ __launch_bounds__(256) void k_gemm_fused(const unsigned short* __restrict__ A,
                                                    const unsigned short* __restrict__ WT,
                                                    unsigned short* __restrict__ WhTf,
                                                    long aOff, long wOff,
                                                    const void* __restrict__ avec,
                                                    const void* __restrict__ adj,
                                                    float* __restrict__ f1,
                                                    float* __restrict__ f2) {
  __shared__ __align__(16) unsigned short tile[4][2][32][17];
  __shared__ float avs[256];
  __shared__ float fp[2][8][32];
  int isbf = detect_bf(adj);
  int head = blockIdx.x % HH;            // XCD pin (matches attn consumer)
  int jb = blockIdx.x / HH;
  A += (size_t)head * aOff; WT += (size_t)head * wOff;
  int rowbase = jb * 32;
  int t = threadIdx.x;
  int w = t >> 6, lane = t & 63;
  int q = lane >> 4, l = lane & 15;
  int colbase = w * 32;
  avs[t] = ldin(avec, (size_t)head * 256 + t, isbf);
  float4v acc[2][2];
#pragma unroll
  for (int rt = 0; rt < 2; rt++)
#pragma unroll
    for (int ct = 0; ct < 2; ct++) { float4v z = {0.f, 0.f, 0.f, 0.f}; acc[rt][ct] = z; }

  for (int kb = 0; kb < K; kb += 32) {
    short8 af[2], bfr[2];
#pragma unroll
    for (int rt = 0; rt < 2; rt++)
      af[rt] = *(const short8*)(A + (size_t)(rowbase + rt * 16 + l) * K + kb + q * 8);
#pragma unroll
    for (int ct = 0; ct < 2; ct++)
      bfr[ct] = *(const short8*)(WT + (size_t)(colbase + ct * 16 + l) * K + kb + q * 8);
#pragma unroll
    for (int rt = 0; rt < 2; rt++)
#pragma unroll
      for (int ct = 0; ct < 2; ct++)
        acc[rt][ct] = __builtin_amdgcn_mfma_f32_16x16x32_bf16(af[rt], bfr[ct], acc[rt][ct], 0, 0, 0);
  }
#pragma unroll
  for (int rt = 0; rt < 2; rt++)
#pragma unroll
    for (int ct = 0; ct < 2; ct++)
#pragma unroll
      for (int reg = 0; reg < 4; reg++)
        tile[w][ct][rt * 16 + q * 4 + reg][l] = f2bf(acc[rt][ct][reg]);
  __syncthreads();
#pragma unroll
  for (int ct = 0; ct < 2; ct++) {
    short8 r8;
#pragma unroll
    for (int i = 0; i < 8; i++) r8[i] = tile[w][ct][q * 8 + i][l];
    size_t chunk = ((size_t)head * (NN / 32) + jb) * 8 + (w * 2 + ct);
    *(short8*)(WhTf + chunk * 512 + lane * 8) = r8;
  }
  {
    int r = t & 31, g = t >> 5;
    int ww = g >> 1, cc = g & 1;
    float s1 = 0.f, s2 = 0.f;
#pragma unroll
    for (int li = 0; li < 16; li++) {
      float v = bf2f(tile[ww][cc][r][li]);
      s1 += v * avs[g * 16 + li];
      s2 += v * avs[128 + g * 16 + li];
    }
    fp[0][g][r] = s1; fp[1][g][r] = s2;
  }
  __syncthreads();
  if (t < 32) {
    float s1 = 0.f, s2 = 0.f;
#pragma unroll
    for (int g2 = 0; g2 < 8; g2++) { s1 += fp[0][g2][t]; s2 += fp[1][g2][t]; }
    f1[head * NN + rowbase + t] = s1;
    f2[head * NN + rowbase + t] = s2;
  }
}

// ---- layer-1 fused GEMM with INLINE REDUCE: A tile (32x128 of h0) built in
//      LDS from layer-0 pnum/pden (S=4) + ELU; h0 never materialized ----
__global__ __launch_bounds__(256) void k_gemm_fused2(
    const unsigned short* __restrict__ pnumIn, const float* __restrict__ pdenIn,
    const unsigned short* __restrict__ WT, unsigned short* __restrict__ WhTf,
    long wOff, const void* __restrict__ avec, const void* __restrict__ adj,
    float* __restrict__ f1, float* __restrict__ f2) {
  constexpr int K = 128;
  __shared__ __align__(16) unsigned short At[32][132];
  __shared__ __align__(16) unsigned short tile[4][2][32][17];
  __shared__ float avs[256];
  __shared__ float fp[2][8][32];
  int isbf = detect_bf(adj);
  int head = blockIdx.x % HH;            // XCD pin (matches attn writer+consumer)
  int jb = blockIdx.x / HH;
  WT += (size_t)head * wOff;
  int rowbase = jb * 32;
  int t = threadIdx.x;
  int w = t >> 6, lane = t & 63;
  int q = lane >> 4, l = lane & 15;
  int colbase = w * 32;
  avs[t] = ldin(avec, (size_t)head * 256 + t, isbf);

  // inline reduce: 16 elems/thread, coalesced pnum/pden loads
#pragma unroll
  for (int c = 0; c < 4; c++) {
    int e_loc = c * 1024 + t * 4;
    int tloc = e_loc >> 8;               // 0..15
    int trb_loc = tloc >> 3, ct = tloc & 7;
    int lane_e = (e_loc >> 2) & 63;
    int row0 = (2 * jb + trb_loc) * 16 + (lane_e >> 4) * 4;
    int col = ct * 16 + (lane_e & 15);
    float sn[4] = {0.f, 0.f, 0.f, 0.f};
    float sd[4] = {0.f, 0.f, 0.f, 0.f};
#pragma unroll
    for (int js = 0; js < 4; js++) {
      size_t sl = (size_t)(js * HH + head);
      ushort4v pv = *(const ushort4v*)(pnumIn + sl * (size_t)(NN * 128) + jb * 4096 + e_loc);
      float4v dv = *(const float4v*)(pdenIn + sl * NN + row0);
      sn[0] += bf2f(pv.x); sn[1] += bf2f(pv.y); sn[2] += bf2f(pv.z); sn[3] += bf2f(pv.w);
      sd[0] += dv.x; sd[1] += dv.y; sd[2] += dv.z; sd[3] += dv.w;
    }
    int lr0 = trb_loc * 16 + (lane_e >> 4) * 4;
#pragma unroll
    for (int r = 0; r < 4; r++) {
      float v = sd[r] > 0.f ? sn[r] / sd[r] : 0.f;
      v = v > 0.f ? v : expm1f(v);        // ELU
      At[lr0 + r][col] = f2bf(v);
    }
  }
  __syncthreads();

  float4v acc[2][2];
#pragma unroll
  for (int rt = 0; rt < 2; rt++)
#pragma unroll
    for (int ct = 0; ct < 2; ct++) { float4v z = {0.f, 0.f, 0.f, 0.f}; acc[rt][ct] = z; }

  for (int kb = 0; kb < K; kb += 32) {
    short8 af[2], bfr[2];
#pragma unroll
    for (int rt = 0; rt < 2; rt++)
      af[rt] = *(const short8*)(&At[rt * 16 + l][kb + q * 8]);
#pragma unroll
    for (int ct = 0; ct < 2; ct++)
      bfr[ct] = *(const short8*)(WT + (size_t)(colbase + ct * 16 + l) * K + kb + q * 8);
#pragma unroll
    for (int rt = 0; rt < 2; rt++)
#pragma unroll
      for (int ct = 0; ct < 2; ct++)
        acc[rt][ct] = __builtin_amdgcn_mfma_f32_16x16x32_bf16(af[rt], bfr[ct], acc[rt][ct], 0, 0, 0);
  }
  __syncthreads();                       // At reads done before tile reuse? (separate arrays; barrier for tile consistency below)
#pragma unroll
  for (int rt = 0; rt < 2; rt++)
#pragma unroll
    for (int ct = 0; ct < 2; ct++)
#pragma unroll
      for (int reg = 0; reg < 4; reg++)
        tile[w][ct][rt * 16 + q * 4 + reg][l] = f2bf(acc[rt][ct][reg]);
  __syncthreads();
#pragma unroll
  for (int ct = 0; ct < 2; ct++) {
    short8 r8;
#pragma unroll
    for (int i = 0; i < 8; i++) r8[i] = tile[w][ct][q * 8 + i][l];
    size_t chunk = ((size_t)head * (NN / 32) + jb) * 8 + (w * 2 + ct);
    *(short8*)(WhTf + chunk * 512 + lane * 8) = r8;
  }
  {
    int r = t & 31, g = t >> 5;
    int ww = g >> 1, cc = g & 1;
    float s1 = 0.f, s2 = 0.f;
#pragma unroll
    for (int li = 0; li < 16; li++) {
      float v = bf2f(tile[ww][cc][r][li]);
      s1 += v * avs[g * 16 + li];
      s2 += v * avs[128 + g * 16 + li];
    }
    fp[0][g][r] = s1; fp[1][g][r] = s2;
  }
  __syncthreads();
  if (t < 32) {
    float s1 = 0.f, s2 = 0.f;
#pragma unroll
    for (int g2 = 0; g2 < 8; g2++) { s1 += fp[0][g2][t]; s2 += fp[1][g2][t]; }
    f1[head * NN + rowbase + t] = s1;
    f2[head * NN + rowbase + t] = s2;
  }
}

// ---- output GEMM with INLINE REDUCE of layer-1 partials (hc never built):
//      block (bx, ks): rows bx*16..+16, cols ks*256..+256 (heads 2ks, 2ks+1) ----
__global__ __launch_bounds__(256) void k_gemm_out_red(
    const unsigned short* __restrict__ pnumIn, const float* __restrict__ pdenIn,
    const unsigned short* __restrict__ WT, float* __restrict__ gpart) {
  constexpr int K = 1024;
  __shared__ __align__(16) unsigned short At[16][260];
  int bx = blockIdx.x, ks = blockIdx.y;
  int t = threadIdx.x;
  int w = t >> 6, lane = t & 63;
  int q = lane >> 4, l = lane & 15;
  // inline reduce: 16 elems/thread from 2 heads' pnum
#pragma unroll
  for (int c = 0; c < 4; c++) {
    int idx = c * 1024 + t * 4;
    int hsel = idx >> 11;
    int rem = idx & 2047;
    int tloc = rem >> 8;                 // ct 0..7
    int lane_e = (rem >> 2) & 63;
    int h = 2 * ks + hsel;
    int row0 = bx * 16 + (lane_e >> 4) * 4;
    int col = hsel * 128 + tloc * 16 + (lane_e & 15);
    float sn[4] = {0.f, 0.f, 0.f, 0.f};
    float sd[4] = {0.f, 0.f, 0.f, 0.f};
#pragma unroll
    for (int js = 0; js < 4; js++) {
      size_t sl = (size_t)(js * HH + h);
      ushort4v pv = *(const ushort4v*)(pnumIn + sl * (size_t)(NN * 128) + (bx * 8 + tloc) * 256 + (rem & 255));
      float4v dv = *(const float4v*)(pdenIn + sl * NN + row0);
      sn[0] += bf2f(pv.x); sn[1] += bf2f(pv.y); sn[2] += bf2f(pv.z); sn[3] += bf2f(pv.w);
      sd[0] += dv.x; sd[1] += dv.y; sd[2] += dv.z; sd[3] += dv.w;
    }
    int lr0 = (lane_e >> 4) * 4;
#pragma unroll
    for (int r = 0; r < 4; r++) {
      float v = sd[r] > 0.f ? sn[r] / sd[r] : 0.f;
      v = v > 0.f ? v : expm1f(v);        // ELU
      At[lr0 + r][col] = f2bf(v);
    }
  }
  __syncthreads();

  int colbase = w * 16;
  float4v acc = {0.f, 0.f, 0.f, 0.f};
  for (int kb = 0; kb < 256; kb += 32) {
    short8 af = *(const short8*)(&At[l][kb + q * 8]);
    short8 bfr = *(const short8*)(WT + (size_t)(colbase + l) * K + ks * 256 + kb + q * 8);
    acc = __builtin_amdgcn_mfma_f32_16x16x32_bf16(af, bfr, acc, 0, 0, 0);
  }
#pragma unroll
  for (int reg = 0; reg < 4; reg++) {
    int r = bx * 16 + q * 4 + reg;
    int n = colbase + l;
    gpart[((size_t)ks * 64 + n) * NN + r] = acc[reg];
  }
}

// ---- combine K-split partials -> WhoTf (frag order) + fo1/fo2 in one pass ----
__global__ __launch_bounds__(256) void k_gemm_red_f12(
    const float* __restrict__ gpart, unsigned short* __restrict__ WhoTf,
    const void* __restrict__ avec, const void* __restrict__ adj,
    float* __restrict__ f1, float* __restrict__ f2) {
  __shared__ float as_[128];
  __shared__ float fp[2][8][32];
  int isbf = detect_bf(adj);
  int jb = blockIdx.x;                   // rows jb*32..+32
  int t = threadIdx.x;
  if (t < 128) as_[t] = ldin(avec, t, isbf);
  __syncthreads();
  int r = t & 31, ng = t >> 5;
  int r_glob = jb * 32 + r;
  float s1 = 0.f, s2 = 0.f;
#pragma unroll
  for (int k = 0; k < 8; k++) {
    int n = ng * 8 + k;
    float s = 0.f;
#pragma unroll
    for (int ks = 0; ks < 4; ks++)
      s += gpart[((size_t)ks * 64 + n) * NN + r_glob];
    int qd = r >> 3, i = r & 7, ct = n >> 4, ld = n & 15;
    WhoTf[((size_t)(jb * 4 + ct)) * 512 + (qd * 16 + ld) * 8 + i] = f2bf(s);
    s1 += s * as_[n];
    s2 += s * as_[64 + n];
  }
  fp[0][ng][r] = s1; fp[1][ng][r] = s2;
  __syncthreads();
  if (t < 32) {
    float a = 0.f, b = 0.f;
#pragma unroll
    for (int g = 0; g < 8; g++) { a += fp[0][g][t]; b += fp[1][g][t]; }
    f1[jb * 32 + t] = a;
    f2[jb * 32 + t] = b;
  }
}

// ---- attention partial (unchanged r15 hot loop): 16-row waves, 64-row
//      blocks, S j-chunks; LDS-staged B double-buffered w/ post-barrier
//      prefetch; ones-MFMA denominator; bf16 frag-order partials; XCD pin ----
template<int DCOL, int S>
__global__ __launch_bounds__(256, 4) void k_attn_part(
    const unsigned* __restrict__ maskT,
    const float* __restrict__ f1g, const float* __restrict__ f2g,
    const unsigned short* __restrict__ WhTf,
    unsigned short* __restrict__ pnum, float* __restrict__ pden, int NH) {
  constexpr int NCT = DCOL / 16;
  constexpr int JCH = NN / S;
  constexpr int NIT = JCH / 32;
  constexpr int CH = NCT * 512;
  constexpr int GR = CH / (256 * 8);
  __shared__ __align__(16) unsigned short Bs[2][CH];
  __shared__ __align__(16) float f2s[JCH];
  __shared__ unsigned ms[NIT * 64];

  int blk = blockIdx.x;
  int head = blk % NH;
  int rest = blk / NH;
  int js = rest % S;
  int bx = rest / S;
  int t = threadIdx.x;
  int w = t >> 6, lane = t & 63;
  int q = lane >> 4, l = lane & 15;
  int rowblk = bx * 64;
  int rowbase = rowblk + w * 16;
  size_t headJB = (size_t)head * (NN / 32);
  int j0 = js * JCH;

  for (int i = t; i < JCH; i += 256) f2s[i] = f2g[head * NN + j0 + i];
  for (int i = t; i < NIT * 64; i += 256)
    ms[i] = maskT[(size_t)((j0 >> 5) + (i >> 6)) * NN + rowblk + (i & 63)];
  float f1c = f1g[head * NN + rowbase + l] * 1.44269504f;

  short8 ones;
#pragma unroll
  for (int i = 0; i < 8; i++) ones[i] = (short)0x3F80;

  float4v acc[NCT];
#pragma unroll
  for (int ct = 0; ct < NCT; ct++) { float4v z = {0.f, 0.f, 0.f, 0.f}; acc[ct] = z; }
  float4v accd = {0.f, 0.f, 0.f, 0.f};

  short8 stg[GR];
  {
    const unsigned short* g0 = WhTf + (headJB + (j0 >> 5)) * (size_t)CH;
#pragma unroll
    for (int g = 0; g < GR; g++) stg[g] = *(const short8*)(g0 + g * 2048 + t * 8);
  }

  int cur = 0;
  for (int it = 0; it < NIT; it++) {
#pragma unroll
    for (int g = 0; g < GR; g++)
      *(short8*)(&Bs[cur][g * 2048 + t * 8]) = stg[g];
    __syncthreads();
    int itn = (it + 1 < NIT) ? it + 1 : 0;
    const unsigned short* gn = WhTf + (headJB + (j0 >> 5) + itn) * (size_t)CH;
#pragma unroll
    for (int g = 0; g < GR; g++) stg[g] = *(const short8*)(gn + g * 2048 + t * 8);

    unsigned mwc = ms[it * 64 + (w * 16 + l)] >> (q * 8);
    float4v fac = *(const float4v*)(&f2s[it * 32 + q * 8]);
    float4v fbc = *(const float4v*)(&f2s[it * 32 + q * 8 + 4]);
    short8 bfr[NCT];
#pragma unroll
    for (int ct = 0; ct < NCT; ct++)
      bfr[ct] = *(const short8*)(&Bs[cur][ct * 512 + lane * 8]);

    float p[8];
#pragma unroll
    for (int i = 0; i < 8; i++) {
      float fv = (i < 4) ? fac[i] : fbc[i - 4];
      float t0 = fmaf(fv, 1.44269504f, f1c);
      t0 = __builtin_amdgcn_fmed3f(t0, 0.2f * t0, 43.f);
      t0 = (mwc & (1u << i)) ? t0 : -200.f;
      p[i] = exp2f(t0);
    }
    union { __hip_bfloat162 b2[4]; short8 s8; } u0;
#pragma unroll
    for (int k = 0; k < 4; k++)
      u0.b2[k] = __float22bfloat162_rn({p[2 * k], p[2 * k + 1]});
    accd = __builtin_amdgcn_mfma_f32_16x16x32_bf16(u0.s8, ones, accd, 0, 0, 0);
#pragma unroll
    for (int ct = 0; ct < NCT; ct++)
      acc[ct] = __builtin_amdgcn_mfma_f32_16x16x32_bf16(u0.s8, bfr[ct], acc[ct], 0, 0, 0);
    cur ^= 1;
  }

  size_t slab = (size_t)(js * NH + head);
  if (l == 0) {
#pragma unroll
    for (int reg = 0; reg < 4; reg++)
      pden[slab * NN + rowbase + q * 4 + reg] = accd[reg];
  }
  int trb = rowbase >> 4;
#pragma unroll
  for (int ct = 0; ct < NCT; ct++) {
    ushort4v u;
    u.x = f2bf(acc[ct].x); u.y = f2bf(acc[ct].y);
    u.z = f2bf(acc[ct].z); u.w = f2bf(acc[ct].w);
    size_t cidx = ((slab * (NN / 16) + trb) * NCT + ct) * 256 + lane * 4;
    *(ushort4v*)(pnum + cidx) = u;
  }
}

// ---- final combine: 4 elems/thread, writes d_out (bf16 or fp32) ----
template<int DCOL, int S>
__global__ __launch_bounds__(256) void k_attn_reduce(
    const unsigned short* __restrict__ pnum, const float* __restrict__ pden,
    void* __restrict__ outg, const void* __restrict__ adj) {
  constexpr int NCT = DCOL / 16;
  int isbf = detect_bf(adj);
  int bi = blockIdx.x;
  int t = threadIdx.x;
  int base = bi * 1024 + t * 4;
  int tile = base >> 8;
  int lane = (base >> 2) & 63;
  int ct = tile % NCT, tr = tile / NCT;
  int q = lane >> 4, l = lane & 15;
  int row0 = tr * 16 + q * 4;
  int col = ct * 16 + l;
  float sn[4] = {0.f, 0.f, 0.f, 0.f};
  float sd[4] = {0.f, 0.f, 0.f, 0.f};
#pragma unroll
  for (int js = 0; js < S; js++) {
    size_t sl = (size_t)js;
    ushort4v pv = *(const ushort4v*)(pnum + sl * (size_t)(NN * DCOL) + base);
    float4v dv = *(const float4v*)(pden + sl * NN + row0);
    sn[0] += bf2f(pv.x); sn[1] += bf2f(pv.y); sn[2] += bf2f(pv.z); sn[3] += bf2f(pv.w);
    sd[0] += dv.x; sd[1] += dv.y; sd[2] += dv.z; sd[3] += dv.w;
  }
#pragma unroll
  for (int r = 0; r < 4; r++) {
    float v = sd[r] > 0.f ? sn[r] / sd[r] : 0.f;
    v = v > 0.f ? v : expm1f(v);           // ELU
    size_t idx = (size_t)(row0 + r) * DCOL + col;
    if (!isbf) ((float*)outg)[idx] = v;
    else ((unsigned short*)outg)[idx] = f2bf(v);
  }
}

extern "C" void kernel_launch(void* const* d_in, const int* in_sizes, int n_in,
                              void* d_out, int out_size, void* d_ws, size_t ws_size,
                              hipStream_t stream) {
  const void* x     = d_in[0];
  const void* adj   = d_in[1];
  const int*  obs   = (const int*)d_in[2];
  // d_in[3] s_mat unused (method='base')
  const void* theta = d_in[4];
  const void* W0    = d_in[5];
  const void* a0    = d_in[6];
  const void* W1    = d_in[7];
  const void* a1    = d_in[8];
  const void* Wo    = d_in[9];
  const void* ao    = d_in[10];

  char* ws = (char*)d_ws;
  size_t off = 0;
  auto alloc = [&](size_t bytes) { void* p = ws + off; off += (bytes + 255) & ~(size_t)255; return p; };
  unsigned*       maskT = (unsigned*)alloc((size_t)NN * 96 * 4);
  unsigned short* h_bf  = (unsigned short*)alloc((size_t)NN * 256 * 2);
  unsigned short* WhTf  = (unsigned short*)alloc((size_t)HH * 128 * NN * 2);
  float*          f1    = (float*)alloc((size_t)HH * NN * 4);
  float*          f2    = (float*)alloc((size_t)HH * NN * 4);
  unsigned short* W0T   = (unsigned short*)alloc((size_t)HH * 128 * 256 * 2);
  unsigned short* W1T   = (unsigned short*)alloc((size_t)HH * 128 * 128 * 2);
  unsigned short* WoT   = (unsigned short*)alloc((size_t)64 * 1024 * 2);
  unsigned short* WhoTf = (unsigned short*)alloc((size_t)64 * NN * 2);
  float*          fo1   = (float*)alloc((size_t)NN * 4);
  float*          fo2   = (float*)alloc((size_t)NN * 4);
  float*          gpart = (float*)alloc((size_t)4 * 64 * NN * 4);
  unsigned short* pnum  = (unsigned short*)alloc((size_t)4 * HH * NN * 128 * 2);
  float*          pden  = (float*)alloc((size_t)32 * NN * 4);

  // 1: mask + merge + weight transposes
  k_maskprep<<<4096, 256, 0, stream>>>(adj, maskT, x, obs, theta, W0, W1, Wo,
                                       h_bf, W0T, W1T, WoT);
  // 2-3: layer 0
  k_gemm_fused<256><<<(NN / 32) * HH, 256, 0, stream>>>(h_bf, W0T, WhTf,
                                                        0, 128 * 256, a0, adj, f1, f2);
  k_attn_part<128, 4><<<(NN / 64) * 4 * HH, 256, 0, stream>>>(maskT, f1, f2, WhTf, pnum, pden, HH);
  // 4-5: layer 1 (reduce of layer 0 folded into the GEMM)
  k_gemm_fused2<<<(NN / 32) * HH, 256, 0, stream>>>(pnum, pden, W1T, WhTf,
                                                    128 * 128, a1, adj, f1, f2);
  k_attn_part<128, 4><<<(NN / 64) * 4 * HH, 256, 0, stream>>>(maskT, f1, f2, WhTf, pnum, pden, HH);
  // 6-7: output GEMM (reduce of layer 1 folded in) + K-combine + f1/f2
  k_gemm_out_red<<<dim3(NN / 16, 4), 256, 0, stream>>>(pnum, pden, WoT, gpart);
  k_gemm_red_f12<<<NN / 32, 256, 0, stream>>>(gpart, WhoTf, ao, adj, fo1, fo2);
  // 8-9: final attention + output
  k_attn_part<64, 32><<<(NN / 64) * 32, 256, 0, stream>>>(maskT, fo1, fo2, WhoTf, pnum, pden, 1);
  k_attn_reduce<64, 32><<<NN * 64 / 1024, 256, 0, stream>>>(pnum, pden, d_out, adj);
}